// Round 13
// baseline (1556.185 us; speedup 1.0000x reference)
//
#include <hip/hip_runtime.h>

// Problem constants (fixed by reference setup_inputs)
#define BB 4
#define LL 4096
#define MM 1024
#define DD 2048
#define SEG 128
#define SM 8            // MM / SEG

typedef float f32x4 __attribute__((ext_vector_type(4)));
#define AGENT __HIP_MEMORY_SCOPE_AGENT

// ---------------------------------------------------------------------------
// Kernel A: per-batch prep (proven R11/R12) + zero the sync words.
// ---------------------------------------------------------------------------
__global__ __launch_bounds__(1024) void prep_kernel(
    const float* __restrict__ bprob,   // (B, L, 2)
    const int*   __restrict__ bmask,   // (B, L)
    float* __restrict__ p_chunked,     // (B, M)
    int*   __restrict__ row_start,     // (B, 1025)
    float* __restrict__ Ppref,         // (B, M)
    int*   __restrict__ sync)          // [0..7] counters, [8..15] done
{
    const int b   = blockIdx.x;
    const int tid = threadIdx.x;
    const int lane = tid & 63;
    const int wid  = tid >> 6;

    if (b == 0 && tid < 16) sync[tid] = 0;

    __shared__ int wsum[16];
    __shared__ int s_total;
    __shared__ int rs_sh[MM + 1];

    rs_sh[tid] = LL;
    if (tid == 0) rs_sh[MM] = LL;

    int4 mv = reinterpret_cast<const int4*>(bmask + b * LL)[tid];
    int ms[4] = { mv.x, mv.y, mv.z, mv.w };
    int s = ms[0] + ms[1] + ms[2] + ms[3];

    int v = s;
    #pragma unroll
    for (int off = 1; off < 64; off <<= 1) {
        int u = __shfl_up(v, off, 64);
        if (lane >= off) v += u;
    }
    if (lane == 63) wsum[wid] = v;
    __syncthreads();
    if (tid == 0) {
        int acc = 0;
        #pragma unroll
        for (int w = 0; w < 16; ++w) { int t = wsum[w]; wsum[w] = acc; acc += t; }
        s_total = acc;
    }
    __syncthreads();

    const int NB = s_total;
    int e = (v - s) + wsum[wid];            // exclusive cumsum before elem

    const int base_l = tid * 4;
    #pragma unroll
    for (int j = 0; j < 4; ++j) {
        int l = base_l + j;
        int m = ms[j];
        int incl = e + m;
        int ci = incl - 1;
        ci = ci < 0 ? 0 : (ci > MM - 1 ? MM - 1 : ci);
        int pci = e - 1;
        pci = pci < 0 ? 0 : (pci > MM - 1 ? MM - 1 : pci);
        if (l == 0 || ci != pci) rs_sh[ci] = l;   // unique writer per t
        int pos = m ? e : (NB + (l - e));
        if (pos < MM) {
            float2 pv = *reinterpret_cast<const float2*>(
                bprob + ((size_t)b * LL + l) * 2);
            float p = fminf(fmaxf(pv.y, 1e-4f), 1.0f - 1e-4f);
            p_chunked[b * MM + pos] = p;
        }
        e = incl;
    }
    __syncthreads();

    row_start[b * (MM + 1) + tid] = rs_sh[tid];
    if (tid == 0) row_start[b * (MM + 1) + MM] = rs_sh[MM];

    // 8-wide in-segment prefix products
    {
        int t = tid;
        float p = p_chunked[b * MM + t];
        float a = (t == 0) ? 0.0f : (1.0f - p);
        float pr = a;
        #pragma unroll
        for (int off = 1; off < SM; off <<= 1) {
            float u = __shfl_up(pr, off, SM);
            if ((t & (SM - 1)) >= off) pr *= u;
        }
        Ppref[b * MM + t] = pr;
    }
}

// ---------------------------------------------------------------------------
// Fused kernel: local scan (regs) -> publish seglast -> central per-(b,dsl)
// carry walk by the seg-127 block -> all blocks scatter directly to out.
// grid = EXACTLY 1024 blocks (dsl 2 x seg 128 x b 4), 256 thr.
// __launch_bounds__(256,6): >=6 blocks/CU -> 1536 slots >= 1024 all-resident
// (deadlock-free). tid0-only spins with s_sleep backoff (R11 storm fix).
// ---------------------------------------------------------------------------
__global__ __launch_bounds__(256, 6) void fused_kernel(
    const float* __restrict__ x,          // (B, M, D)
    const float* __restrict__ p_chunked,  // (B, M)
    const float* __restrict__ Ppref,      // (B, M)
    const int*   __restrict__ row_start,  // (B, 1025)
    float* __restrict__ locbuf,           // (B,2,SEG,1024): seglast -> carry-in
    float* __restrict__ yM1,              // (B,2,1024)
    int*   __restrict__ sync,             // [0..7] counter, [8..15] done
    float* __restrict__ out)              // (B, L, D)
{
    const int sid = blockIdx.x;
    const int dsl = sid & 1;
    const int seg = (sid >> 1) & (SEG - 1);
    const int b   = sid >> 8;
    const int tid = threadIdx.x;
    const int d0  = dsl * 1024 + tid * 4;
    const int t0  = seg * SM;
    const int bd  = b * 2 + dsl;

    __shared__ float sp[SM], spp[SM], sPf[SEG];
    __shared__ int rs[SM + 1];
    if (tid < SM) {
        sp[tid]  = p_chunked[b * MM + t0 + tid];
        spp[tid] = Ppref[b * MM + t0 + tid];
    }
    if (tid < SM + 1) rs[tid] = row_start[b * (MM + 1) + t0 + tid];
    if (tid < SEG) sPf[tid] = Ppref[b * MM + tid * SM + SM - 1];
    __syncthreads();

    // ---- local segment scan, rows in registers ----
    f32x4 yl[SM];
    f32x4 prev = {0.0f, 0.0f, 0.0f, 0.0f};
    const size_t xbase = ((size_t)b * MM + t0) * DD + d0;
    #pragma unroll
    for (int i = 0; i < SM; ++i) {
        float p = sp[i];
        float ac, bc;
        if (i == 0) { ac = (seg == 0) ? 0.0f : (1.0f - p); bc = (seg == 0) ? 1.0f : p; }
        else        { ac = 1.0f - p; bc = p; }
        f32x4 xt = *reinterpret_cast<const f32x4*>(x + xbase + (size_t)i * DD);
        prev = ac * prev + bc * xt;
        yl[i] = prev;
    }

    // ---- publish segment-last ----
    float* slot = locbuf + ((size_t)bd * SEG + seg) * 1024 + tid * 4;
    #pragma unroll
    for (int k = 0; k < 4; ++k)
        __hip_atomic_store(&slot[k], prev[k], __ATOMIC_RELAXED, AGENT);
    __syncthreads();    // compiler drains vmcnt before barrier -> stores visible
    if (tid == 0)
        __hip_atomic_fetch_add(&sync[bd], 1, __ATOMIC_RELEASE, AGENT);

    // ---- resolve carry-in ----
    f32x4 c = {0.0f, 0.0f, 0.0f, 0.0f};
    if (seg == SEG - 1) {
        // central walk for this (b,dsl); in-place seglast -> carry-in
        if (tid == 0) {
            while (__hip_atomic_load(&sync[bd], __ATOMIC_ACQUIRE, AGENT) < SEG)
                __builtin_amdgcn_s_sleep(2);
        }
        __syncthreads();
        f32x4 run = {0.0f, 0.0f, 0.0f, 0.0f};
        float* base = locbuf + (size_t)bd * SEG * 1024 + tid * 4;
        for (int s = 0; s < SEG; ++s) {
            float* a = base + (size_t)s * 1024;
            f32x4 last;
            #pragma unroll
            for (int k = 0; k < 4; ++k)
                last[k] = __hip_atomic_load(&a[k], __ATOMIC_RELAXED, AGENT);
            if (s == SEG - 1) c = run;          // own carry-in
            #pragma unroll
            for (int k = 0; k < 4; ++k)
                __hip_atomic_store(&a[k], run[k], __ATOMIC_RELAXED, AGENT);
            run = sPf[s] * run + last;
        }
        float* yb = yM1 + (size_t)bd * 1024 + tid * 4;
        #pragma unroll
        for (int k = 0; k < 4; ++k)
            __hip_atomic_store(&yb[k], run[k], __ATOMIC_RELAXED, AGENT);
        __syncthreads();
        if (tid == 0)
            __hip_atomic_store(&sync[8 + bd], 1, __ATOMIC_RELEASE, AGENT);
    } else {
        if (tid == 0) {
            while (__hip_atomic_load(&sync[8 + bd], __ATOMIC_ACQUIRE, AGENT) == 0)
                __builtin_amdgcn_s_sleep(2);
        }
        __syncthreads();
        #pragma unroll
        for (int k = 0; k < 4; ++k)
            c[k] = __hip_atomic_load(&slot[k], __ATOMIC_RELAXED, AGENT);
    }

    // ---- scatter own chunks to their contiguous out-row ranges ----
    #pragma unroll
    for (int i = 0; i < SM; ++i) {
        int t = t0 + i;
        if (t == MM - 1) continue;            // tail handled below
        f32x4 v = yl[i] + spp[i] * c;
        for (int l = rs[i]; l < rs[i + 1]; ++l)
            *reinterpret_cast<f32x4*>(out + ((size_t)b * LL + l) * DD + d0) = v;
    }

    // ---- tail share: rows [row_start[M-1], LL) all equal yM1 ----
    {
        f32x4 v;
        float* yb = yM1 + (size_t)bd * 1024 + tid * 4;
        #pragma unroll
        for (int k = 0; k < 4; ++k)
            v[k] = __hip_atomic_load(&yb[k], __ATOMIC_RELAXED, AGENT);
        int rstail = row_start[b * (MM + 1) + (MM - 1)];
        for (int l = rstail + seg; l < LL; l += SEG)
            *reinterpret_cast<f32x4*>(out + ((size_t)b * LL + l) * DD + d0) = v;
    }
}

// ---------------------------------------------------------------------------
extern "C" void kernel_launch(void* const* d_in, const int* in_sizes, int n_in,
                              void* d_out, int out_size, void* d_ws, size_t ws_size,
                              hipStream_t stream) {
    const float* x     = (const float*)d_in[0];   // chunked_states (B,M,D) f32
    const float* bprob = (const float*)d_in[1];   // boundary_prob  (B,L,2) f32
    const int*   bmask = (const int*)d_in[2];     // boundary_mask  (B,L) int

    float* out = (float*)d_out;

    // workspace layout (~4.3 MB)
    float* locbuf    = (float*)d_ws;                          // B*2*SEG*1024
    float* yM1       = locbuf + (size_t)BB * 2 * SEG * 1024;  // B*2*1024
    float* p_chunked = yM1 + BB * 2 * 1024;                   // B*M
    float* Ppref     = p_chunked + BB * MM;                   // B*M
    int*   row_start = (int*)(Ppref + BB * MM);               // B*1025
    int*   sync      = row_start + BB * (MM + 1);             // 16 ints

    prep_kernel<<<BB, 1024, 0, stream>>>(bprob, bmask, p_chunked, row_start,
                                         Ppref, sync);
    fused_kernel<<<BB * 2 * SEG, 256, 0, stream>>>(
        x, p_chunked, Ppref, row_start, locbuf, yM1, sync, out);
}

// Round 14
// 338.663 us; speedup vs baseline: 4.5951x; 4.5951x over previous
//
#include <hip/hip_runtime.h>

// Problem constants (fixed by reference setup_inputs)
#define BB 4
#define LL 4096
#define MM 1024
#define DD 2048
#define SEG 128
#define SM 8            // MM / SEG
#define NSCAN (BB * SEG * 2)
#define BCAST 1024

typedef float f32x4 __attribute__((ext_vector_type(4)));

// ---------------------------------------------------------------------------
// Kernel A: per-batch prep (proven R11/R12).
// ---------------------------------------------------------------------------
__global__ __launch_bounds__(1024) void prep_kernel(
    const float* __restrict__ bprob,   // (B, L, 2)
    const int*   __restrict__ bmask,   // (B, L)
    float* __restrict__ p_chunked,     // (B, M)
    int*   __restrict__ row_start,     // (B, 1025)
    float* __restrict__ Ppref)         // (B, M)
{
    const int b   = blockIdx.x;
    const int tid = threadIdx.x;
    const int lane = tid & 63;
    const int wid  = tid >> 6;

    __shared__ int wsum[16];
    __shared__ int s_total;
    __shared__ int rs_sh[MM + 1];

    rs_sh[tid] = LL;
    if (tid == 0) rs_sh[MM] = LL;

    int4 mv = reinterpret_cast<const int4*>(bmask + b * LL)[tid];
    int ms[4] = { mv.x, mv.y, mv.z, mv.w };
    int s = ms[0] + ms[1] + ms[2] + ms[3];

    int v = s;
    #pragma unroll
    for (int off = 1; off < 64; off <<= 1) {
        int u = __shfl_up(v, off, 64);
        if (lane >= off) v += u;
    }
    if (lane == 63) wsum[wid] = v;
    __syncthreads();
    if (tid == 0) {
        int acc = 0;
        #pragma unroll
        for (int w = 0; w < 16; ++w) { int t = wsum[w]; wsum[w] = acc; acc += t; }
        s_total = acc;
    }
    __syncthreads();

    const int NB = s_total;
    int e = (v - s) + wsum[wid];

    const int base_l = tid * 4;
    #pragma unroll
    for (int j = 0; j < 4; ++j) {
        int l = base_l + j;
        int m = ms[j];
        int incl = e + m;
        int ci = incl - 1;
        ci = ci < 0 ? 0 : (ci > MM - 1 ? MM - 1 : ci);
        int pci = e - 1;
        pci = pci < 0 ? 0 : (pci > MM - 1 ? MM - 1 : pci);
        if (l == 0 || ci != pci) rs_sh[ci] = l;
        int pos = m ? e : (NB + (l - e));
        if (pos < MM) {
            float2 pv = *reinterpret_cast<const float2*>(
                bprob + ((size_t)b * LL + l) * 2);
            float p = fminf(fmaxf(pv.y, 1e-4f), 1.0f - 1e-4f);
            p_chunked[b * MM + pos] = p;
        }
        e = incl;
    }
    __syncthreads();

    row_start[b * (MM + 1) + tid] = rs_sh[tid];
    if (tid == 0) row_start[b * (MM + 1) + MM] = rs_sh[MM];

    {
        int t = tid;
        float p = p_chunked[b * MM + t];
        float a = (t == 0) ? 0.0f : (1.0f - p);
        float pr = a;
        #pragma unroll
        for (int off = 1; off < SM; off <<= 1) {
            float u = __shfl_up(pr, off, SM);
            if ((t & (SM - 1)) >= off) pr *= u;
        }
        Ppref[b * MM + t] = pr;
    }
}

// ---------------------------------------------------------------------------
// Kernel B: seglast pass. DIAGNOSTIC: reps idempotent repeats.
// ---------------------------------------------------------------------------
__global__ __launch_bounds__(256) void seglast_kernel(
    const float* __restrict__ x,          // (B, M, D)
    const float* __restrict__ p_chunked,  // (B, M)
    float* __restrict__ seglast,          // (B, SEG, D)
    int reps)
{
    const int tid = threadIdx.x;
    const int d0  = blockIdx.x * 1024 + tid * 4;
    const int seg = blockIdx.y;
    const int b   = blockIdx.z;
    const int t0  = seg * SM;

    __shared__ float sp[SM];
    if (tid < SM) sp[tid] = p_chunked[b * MM + t0 + tid];
    __syncthreads();

    const size_t base = ((size_t)b * MM + t0) * DD + d0;

    for (int r = 0; r < reps; ++r) {
        f32x4 prev = {0.0f, 0.0f, 0.0f, 0.0f};
        #pragma unroll
        for (int i = 0; i < SM; ++i) {
            float p = sp[i];
            float ac, bc;
            if (i == 0) { ac = (seg == 0) ? 0.0f : (1.0f - p); bc = (seg == 0) ? 1.0f : p; }
            else        { ac = 1.0f - p; bc = p; }
            f32x4 xt = *reinterpret_cast<const f32x4*>(x + base + (size_t)i * DD);
            prev = ac * prev + bc * xt;
        }
        *reinterpret_cast<f32x4*>(seglast + ((size_t)b * SEG + seg) * DD + d0) = prev;
    }
}

// ---------------------------------------------------------------------------
// Kernel C: carry recurrence, OUT-OF-PLACE (buf -> carrybuf, + yM1).
// DIAGNOSTIC: reps idempotent repeats.
// ---------------------------------------------------------------------------
__global__ __launch_bounds__(256) void carry_kernel(
    const float* __restrict__ buf,        // (B, SEG, D) seglast (unchanged)
    const float* __restrict__ Ppref,      // (B, M)
    float* __restrict__ carrybuf,         // (B, SEG, D) carry-in per segment
    float* __restrict__ yM1,              // (B, D)
    int reps)
{
    int idx = blockIdx.x * 256 + threadIdx.x;   // over B*D/2
    int b  = idx / (DD / 2);
    int d2 = (idx % (DD / 2)) * 2;

    for (int r = 0; r < reps; ++r) {
        float2 run = make_float2(0.0f, 0.0f);
        #pragma unroll 8
        for (int s = 0; s < SEG; ++s) {
            float2 last = *reinterpret_cast<const float2*>(
                buf + ((size_t)b * SEG + s) * DD + d2);
            *reinterpret_cast<float2*>(
                carrybuf + ((size_t)b * SEG + s) * DD + d2) = run;
            float Pf = Ppref[b * MM + s * SM + SM - 1];
            run.x = fmaf(Pf, run.x, last.x);
            run.y = fmaf(Pf, run.y, last.y);
        }
        *reinterpret_cast<float2*>(yM1 + (size_t)b * DD + d2) = run;
    }
}

// ---------------------------------------------------------------------------
// Kernel D: direct scatter (R12 logic). DIAGNOSTIC: reps idempotent repeats.
// ---------------------------------------------------------------------------
__global__ __launch_bounds__(256) void scatter_kernel(
    const float* __restrict__ x,          // (B, M, D)
    const float* __restrict__ p_chunked,  // (B, M)
    const int*   __restrict__ row_start,  // (B, 1025)
    const float* __restrict__ carry,      // (B, SEG, D)
    const float* __restrict__ yM1,        // (B, D)
    float* __restrict__ out,              // (B, L, D)
    int reps)
{
    const int id  = blockIdx.x;
    const int tid = threadIdx.x;

    if (id < NSCAN) {
        const int dsl = id & 1;
        const int seg = (id >> 1) & (SEG - 1);
        const int b   = id >> 8;
        const int d0  = dsl * 1024 + tid * 4;
        const int t0  = seg * SM;

        __shared__ float sp[SM];
        __shared__ int   rs[SM + 1];
        if (tid < SM) sp[tid] = p_chunked[b * MM + t0 + tid];
        if (tid < SM + 1) rs[tid] = row_start[b * (MM + 1) + t0 + tid];
        __syncthreads();

        const size_t base = ((size_t)b * MM + t0) * DD + d0;

        for (int r = 0; r < reps; ++r) {
            f32x4 prev = *reinterpret_cast<const f32x4*>(
                carry + ((size_t)(b * SEG + seg)) * DD + d0);
            #pragma unroll
            for (int i = 0; i < SM; ++i) {
                float p = sp[i];
                float ac, bc;
                if (i == 0) { ac = (seg == 0) ? 0.0f : (1.0f - p); bc = (seg == 0) ? 1.0f : p; }
                else        { ac = 1.0f - p; bc = p; }
                f32x4 xt = *reinterpret_cast<const f32x4*>(x + base + (size_t)i * DD);
                prev = ac * prev + bc * xt;

                int t = t0 + i;
                if (t == MM - 1) continue;
                int l0r = rs[i], l1r = rs[i + 1];
                for (int l = l0r; l < l1r; ++l)
                    *reinterpret_cast<f32x4*>(out + ((size_t)b * LL + l) * DD + d0) = prev;
            }
        }
    } else {
        const int j    = id - NSCAN;
        const int g    = j & 7;
        const int chnk = j >> 3;
        const int b    = g >> 1;
        const int dsl  = g & 1;
        const int d0   = dsl * 1024 + tid * 4;

        for (int r = 0; r < reps; ++r) {
            f32x4 v = *reinterpret_cast<const f32x4*>(yM1 + (size_t)b * DD + d0);
            const int l0 = row_start[b * (MM + 1) + (MM - 1)];
            for (int l = l0 + chnk; l < LL; l += 128)
                *reinterpret_cast<f32x4*>(out + ((size_t)b * LL + l) * DD + d0) = v;
        }
    }
}

// ---------------------------------------------------------------------------
extern "C" void kernel_launch(void* const* d_in, const int* in_sizes, int n_in,
                              void* d_out, int out_size, void* d_ws, size_t ws_size,
                              hipStream_t stream) {
    const float* x     = (const float*)d_in[0];
    const float* bprob = (const float*)d_in[1];
    const int*   bmask = (const int*)d_in[2];

    float* out = (float*)d_out;

    // workspace layout (~8.5 MB)
    float* buf       = (float*)d_ws;                          // B*SEG*D seglast
    float* carrybuf  = buf + (size_t)BB * SEG * DD;           // B*SEG*D carry
    float* yM1       = carrybuf + (size_t)BB * SEG * DD;      // B*D
    float* p_chunked = yM1 + BB * DD;                         // B*M
    float* Ppref     = p_chunked + BB * MM;                   // B*M
    int*   row_start = (int*)(Ppref + BB * MM);               // B*1025

    prep_kernel<<<BB, 1024, 0, stream>>>(bprob, bmask, p_chunked, row_start, Ppref);
    seglast_kernel<<<dim3(DD / 1024, SEG, BB), 256, 0, stream>>>(x, p_chunked, buf, 16);
    carry_kernel<<<(BB * DD / 2) / 256, 256, 0, stream>>>(buf, Ppref, carrybuf, yM1, 32);
    scatter_kernel<<<NSCAN + BCAST, 256, 0, stream>>>(
        x, p_chunked, row_start, carrybuf, yM1, out, 4);
}

// Round 15
// 44.208 us; speedup vs baseline: 35.2017x; 7.6607x over previous
//
#include <hip/hip_runtime.h>

// Problem constants (fixed by reference setup_inputs)
#define BB 4
#define LL 4096
#define MM 1024
#define DD 2048
#define SEG 128
#define SM 8            // MM / SEG
#define NSCAN (BB * SEG * 2)
#define BCAST 1024
#define EXIT_EPS 1e-7f

typedef float f32x4 __attribute__((ext_vector_type(4)));

// ---------------------------------------------------------------------------
// Kernel A: per-batch prep (proven R11-R14).
//  - cumsum of boundary_mask; scatter clipped p (stable partition)
//  - row_start[b][t]; Ppref[b][t] (8-wide in-segment prefix products)
// ---------------------------------------------------------------------------
__global__ __launch_bounds__(1024) void prep_kernel(
    const float* __restrict__ bprob,   // (B, L, 2)
    const int*   __restrict__ bmask,   // (B, L)
    float* __restrict__ p_chunked,     // (B, M)
    int*   __restrict__ row_start,     // (B, 1025)
    float* __restrict__ Ppref)         // (B, M)
{
    const int b   = blockIdx.x;
    const int tid = threadIdx.x;
    const int lane = tid & 63;
    const int wid  = tid >> 6;

    __shared__ int wsum[16];
    __shared__ int s_total;
    __shared__ int rs_sh[MM + 1];

    rs_sh[tid] = LL;
    if (tid == 0) rs_sh[MM] = LL;

    int4 mv = reinterpret_cast<const int4*>(bmask + b * LL)[tid];
    int ms[4] = { mv.x, mv.y, mv.z, mv.w };
    int s = ms[0] + ms[1] + ms[2] + ms[3];

    int v = s;
    #pragma unroll
    for (int off = 1; off < 64; off <<= 1) {
        int u = __shfl_up(v, off, 64);
        if (lane >= off) v += u;
    }
    if (lane == 63) wsum[wid] = v;
    __syncthreads();
    if (tid == 0) {
        int acc = 0;
        #pragma unroll
        for (int w = 0; w < 16; ++w) { int t = wsum[w]; wsum[w] = acc; acc += t; }
        s_total = acc;
    }
    __syncthreads();

    const int NB = s_total;
    int e = (v - s) + wsum[wid];

    const int base_l = tid * 4;
    #pragma unroll
    for (int j = 0; j < 4; ++j) {
        int l = base_l + j;
        int m = ms[j];
        int incl = e + m;
        int ci = incl - 1;
        ci = ci < 0 ? 0 : (ci > MM - 1 ? MM - 1 : ci);
        int pci = e - 1;
        pci = pci < 0 ? 0 : (pci > MM - 1 ? MM - 1 : pci);
        if (l == 0 || ci != pci) rs_sh[ci] = l;
        int pos = m ? e : (NB + (l - e));
        if (pos < MM) {
            float2 pv = *reinterpret_cast<const float2*>(
                bprob + ((size_t)b * LL + l) * 2);
            float p = fminf(fmaxf(pv.y, 1e-4f), 1.0f - 1e-4f);
            p_chunked[b * MM + pos] = p;
        }
        e = incl;
    }
    __syncthreads();

    row_start[b * (MM + 1) + tid] = rs_sh[tid];
    if (tid == 0) row_start[b * (MM + 1) + MM] = rs_sh[MM];

    {
        int t = tid;
        float p = p_chunked[b * MM + t];
        float a = (t == 0) ? 0.0f : (1.0f - p);
        float pr = a;
        #pragma unroll
        for (int off = 1; off < SM; off <<= 1) {
            float u = __shfl_up(pr, off, SM);
            if ((t & (SM - 1)) >= off) pr *= u;
        }
        Ppref[b * MM + t] = pr;
    }
}

// ---------------------------------------------------------------------------
// Kernel B: per-segment scan emitting ONLY the segment-end value.
// grid = (2, 128, 4) = 1024 blocks, block = 256, f32x4 per thread.
// seglast layout: (b, dsl, seg, 1024) so each walk's slice is compact.
// ---------------------------------------------------------------------------
__global__ __launch_bounds__(256) void seglast_kernel(
    const float* __restrict__ x,          // (B, M, D)
    const float* __restrict__ p_chunked,  // (B, M)
    float* __restrict__ seglast)          // (B, 2, SEG, 1024)
{
    const int tid = threadIdx.x;
    const int dsl = blockIdx.x;
    const int d0  = dsl * 1024 + tid * 4;
    const int seg = blockIdx.y;
    const int b   = blockIdx.z;
    const int t0  = seg * SM;

    __shared__ float sp[SM];
    if (tid < SM) sp[tid] = p_chunked[b * MM + t0 + tid];
    __syncthreads();

    const size_t base = ((size_t)b * MM + t0) * DD + d0;

    f32x4 prev = {0.0f, 0.0f, 0.0f, 0.0f};
    #pragma unroll
    for (int i = 0; i < SM; ++i) {
        float p = sp[i];
        float ac, bc;
        if (i == 0) { ac = (seg == 0) ? 0.0f : (1.0f - p); bc = (seg == 0) ? 1.0f : p; }
        else        { ac = 1.0f - p; bc = p; }
        f32x4 xt = *reinterpret_cast<const f32x4*>(x + base + (size_t)i * DD);
        prev = ac * prev + bc * xt;
    }
    *reinterpret_cast<f32x4*>(
        seglast + (((size_t)(b * 2 + dsl) * SEG + seg)) * 1024 + tid * 4) = prev;
}

// ---------------------------------------------------------------------------
// Early-exit backward lookback: carry-in before segment `seg` for (b,dsl).
// c = sum_{j<seg} (prod_{k=j+1..seg-1} Pf_k) * seglast_j ; walk j backward,
// mult *= Pf_j after each term; wave-uniform exit when mult < EXIT_EPS.
// Typical depth ~2-3 (Pf ~ 3e-4 for uniform p); worst case full walk.
// ---------------------------------------------------------------------------
static __device__ __forceinline__ f32x4 lookback(
    const float* __restrict__ seglast, const float* __restrict__ sPf,
    int bd, int seg, int tid)
{
    f32x4 c = {0.0f, 0.0f, 0.0f, 0.0f};
    float mult = 1.0f;
    const float* base = seglast + (size_t)bd * SEG * 1024 + tid * 4;
    for (int j = seg - 1; j >= 0; --j) {
        f32x4 sl = *reinterpret_cast<const f32x4*>(base + (size_t)j * 1024);
        c += mult * sl;
        mult *= sPf[j];
        if (mult < EXIT_EPS) break;       // uniform scalar branch
    }
    return c;
}

// ---------------------------------------------------------------------------
// Kernel C: direct scatter with inline early-exit lookback.
// Blocks [0,NSCAN): re-scan x (LLC-hot) seeded with walked carry-in, write
//   chunk rows to contiguous out ranges (chunk M-1 skipped).
// Blocks [NSCAN,NSCAN+BCAST): walk full inclusive y[M-1], stream the tail.
// No cross-block waits; all inputs from completed kernels.
// ---------------------------------------------------------------------------
__global__ __launch_bounds__(256) void scatter_kernel(
    const float* __restrict__ x,          // (B, M, D)
    const float* __restrict__ p_chunked,  // (B, M)
    const float* __restrict__ Ppref,      // (B, M)
    const int*   __restrict__ row_start,  // (B, 1025)
    const float* __restrict__ seglast,    // (B, 2, SEG, 1024)
    float* __restrict__ out)              // (B, L, D)
{
    const int id  = blockIdx.x;
    const int tid = threadIdx.x;

    __shared__ float sPf[SEG];

    if (id < NSCAN) {
        const int dsl = id & 1;
        const int seg = (id >> 1) & (SEG - 1);
        const int b   = id >> 8;
        const int d0  = dsl * 1024 + tid * 4;
        const int t0  = seg * SM;
        const int bd  = b * 2 + dsl;

        __shared__ float sp[SM];
        __shared__ int   rs[SM + 1];
        if (tid < SM) sp[tid] = p_chunked[b * MM + t0 + tid];
        if (tid < SM + 1) rs[tid] = row_start[b * (MM + 1) + t0 + tid];
        if (tid < SEG) sPf[tid] = Ppref[b * MM + tid * SM + SM - 1];
        __syncthreads();

        f32x4 prev = lookback(seglast, sPf, bd, seg, tid);

        const size_t base = ((size_t)b * MM + t0) * DD + d0;
        #pragma unroll
        for (int i = 0; i < SM; ++i) {
            float p = sp[i];
            float ac, bc;
            if (i == 0) { ac = (seg == 0) ? 0.0f : (1.0f - p); bc = (seg == 0) ? 1.0f : p; }
            else        { ac = 1.0f - p; bc = p; }
            f32x4 xt = *reinterpret_cast<const f32x4*>(x + base + (size_t)i * DD);
            prev = ac * prev + bc * xt;

            int t = t0 + i;
            if (t == MM - 1) continue;        // tail handled by broadcast blocks
            int l0r = rs[i], l1r = rs[i + 1];
            for (int l = l0r; l < l1r; ++l)
                *reinterpret_cast<f32x4*>(out + ((size_t)b * LL + l) * DD + d0) = prev;
        }
    } else {
        // tail broadcast: rows [row_start[M-1], LL) all equal y[M-1]
        const int j    = id - NSCAN;          // 0..BCAST-1
        const int g    = j & 7;               // (b, dsl)
        const int chnk = j >> 3;              // 0..127
        const int b    = g >> 1;
        const int dsl  = g & 1;
        const int d0   = dsl * 1024 + tid * 4;
        const int bd   = b * 2 + dsl;

        if (tid < SEG) sPf[tid] = Ppref[b * MM + tid * SM + SM - 1];
        __syncthreads();

        // y[M-1] = lookback over ALL 128 segments (seg = SEG in walk terms)
        f32x4 v = lookback(seglast, sPf, bd, SEG, tid);

        const int l0 = row_start[b * (MM + 1) + (MM - 1)];
        for (int l = l0 + chnk; l < LL; l += 128)
            *reinterpret_cast<f32x4*>(out + ((size_t)b * LL + l) * DD + d0) = v;
    }
}

// ---------------------------------------------------------------------------
extern "C" void kernel_launch(void* const* d_in, const int* in_sizes, int n_in,
                              void* d_out, int out_size, void* d_ws, size_t ws_size,
                              hipStream_t stream) {
    const float* x     = (const float*)d_in[0];
    const float* bprob = (const float*)d_in[1];
    const int*   bmask = (const int*)d_in[2];

    float* out = (float*)d_out;

    // workspace layout (~4.3 MB)
    float* seglast   = (float*)d_ws;                          // B*2*SEG*1024
    float* p_chunked = seglast + (size_t)BB * 2 * SEG * 1024; // B*M
    float* Ppref     = p_chunked + BB * MM;                   // B*M
    int*   row_start = (int*)(Ppref + BB * MM);               // B*1025

    prep_kernel<<<BB, 1024, 0, stream>>>(bprob, bmask, p_chunked, row_start, Ppref);
    seglast_kernel<<<dim3(2, SEG, BB), 256, 0, stream>>>(x, p_chunked, seglast);
    scatter_kernel<<<NSCAN + BCAST, 256, 0, stream>>>(
        x, p_chunked, Ppref, row_start, seglast, out);
}